// Round 19
// baseline (561.423 us; speedup 1.0000x reference)
//
#include <hip/hip_runtime.h>
#include <math.h>

#define T_STEPS 48
#define N_NODES 1000
#define E_EDGES 32000
#define DIN     32
#define H_DIM   64

// ---- workspace layout (4-byte units) ----
#define O_INDEG  0         // int[1000]
#define O_FILL   1024      // int[1000]
#define O_ROWPTR 2048      // int[1001]
#define O_CSRC   4096      // int[32000]
#define O_CNORM  36864     // f32[32000]
#define O_DINV   69632     // f32[1000]
#define O_SELF   70656     // f32[1000]
#define O_BUF0   71680                    // f32[48*64000]
#define O_BUF1   (71680 + 3072000)        // f32[48*64000]
#define O_HSB    (71680 + 6144000)        // bf16[48*64000]
#define O_SHI    (O_HSB + 1536000)        // bf16[1008*1024]
#define O_SLO    (O_SHI + 516096)         // bf16[1008*1024]
#define O_TT     (O_SLO + 516096)         // bf16[48*64*1024]
#define WS_NEED_BIG ((size_t)(O_TT + 1572864) * 4)

typedef __attribute__((ext_vector_type(8))) short short8;       // 8 bf16
typedef __attribute__((ext_vector_type(4))) float f32x4;
typedef __attribute__((ext_vector_type(4))) unsigned int uint32x4;

__device__ __forceinline__ float sigmf(float v) { return 1.0f / (1.0f + __expf(-v)); }
__device__ __forceinline__ unsigned short bf16rne(float f) {
  unsigned u = __float_as_uint(f);
  return (unsigned short)((u + 0x7fff + ((u >> 16) & 1)) >> 16);
}

// ---------------- setup (R17-proven 4-kernel chain) ----------------
__global__ void k_zero(int* __restrict__ p) { p[blockIdx.x * 256 + threadIdx.x] = 0; }

__global__ void k_count(const int* __restrict__ ei, int* __restrict__ indeg) {
  int e = blockIdx.x * 256 + threadIdx.x;
  if (e < E_EDGES) atomicAdd(&indeg[ei[E_EDGES + e]], 1);
}

__global__ void k_scan(const int* __restrict__ indeg, int* __restrict__ rowptr,
                       float* __restrict__ dinv, float* __restrict__ selfn) {
  __shared__ int sdat[1024];
  int tid = threadIdx.x;
  int v = (tid < N_NODES) ? indeg[tid] : 0;
  sdat[tid] = v;
  __syncthreads();
  for (int off = 1; off < 1024; off <<= 1) {
    int add = (tid >= off) ? sdat[tid - off] : 0;
    __syncthreads();
    sdat[tid] += add;
    __syncthreads();
  }
  if (tid < N_NODES) {
    rowptr[tid + 1] = sdat[tid];
    float di = rsqrtf((float)(v + 1));
    dinv[tid] = di;
    selfn[tid] = di * di;
  }
  if (tid == 0) rowptr[0] = 0;
}

__global__ void k_scatter(const int* __restrict__ ei, const int* __restrict__ rowptr,
                          int* __restrict__ fill, const float* __restrict__ dinv,
                          int* __restrict__ csrc, float* __restrict__ cnorm) {
  int e = blockIdx.x * 256 + threadIdx.x;
  if (e >= E_EDGES) return;
  int s = ei[e], d = ei[E_EDGES + e];
  int pos = atomicAdd(&fill[d], 1);
  int idx = rowptr[d] + pos;
  csrc[idx] = s;
  cnorm[idx] = dinv[s] * dinv[d];
}

// ---------------- dense S build: S[n][m] bf16 hi/lo, self-loop on diag ----------------
__global__ void __launch_bounds__(256) k_sden(const int* __restrict__ rowptr,
                                              const int* __restrict__ csrc,
                                              const float* __restrict__ cnorm,
                                              const float* __restrict__ selfn,
                                              unsigned short* __restrict__ Shi,
                                              unsigned short* __restrict__ Slo) {
  __shared__ int   es[512];
  __shared__ float ew[512];
  const int n = blockIdx.x;            // 0..1007 (rows >= 1000 are zero padding)
  const int tid = threadIdx.x;
  int cnt = 0;
  if (n < N_NODES) {
    const int a = rowptr[n], b = rowptr[n + 1];
    cnt = b - a; if (cnt > 512) cnt = 512;
    for (int i = tid; i < cnt; i += 256) { es[i] = csrc[a + i]; ew[i] = cnorm[a + i]; }
  }
  __syncthreads();
  for (int c = tid; c < 1024; c += 256) {
    float s = 0.f;
    if (n < N_NODES) {
      if (c == n) s = selfn[n];
      for (int e = 0; e < cnt; ++e) if (es[e] == c) s += ew[e];   // duplicates summed
    }
    const unsigned short hb = bf16rne(s);
    const float hf = __uint_as_float(((unsigned)hb) << 16);
    Shi[n * 1024 + c] = hb;
    Slo[n * 1024 + c] = bf16rne(s - hf);
  }
}

// ---------------- transpose+cvt: T f32[48000][64] -> Tt bf16[48][64][1024] ----------------
__global__ void __launch_bounds__(256) k_tr(const float* __restrict__ T,
                                            unsigned short* __restrict__ Tt) {
  __shared__ float lds[128][65];
  const int t = blockIdx.x >> 3, mc = (blockIdx.x & 7) * 128;
  const int tid = threadIdx.x;
  for (int i = tid; i < 2048; i += 256) {
    const int m = i >> 4, h4 = (i & 15) * 4;
    const int gm = mc + m;
    float4 v = make_float4(0.f, 0.f, 0.f, 0.f);
    if (gm < N_NODES) v = *(const float4*)&T[(size_t)(t * 1000 + gm) * 64 + h4];
    lds[m][h4] = v.x; lds[m][h4 + 1] = v.y; lds[m][h4 + 2] = v.z; lds[m][h4 + 3] = v.w;
  }
  __syncthreads();
  for (int i = tid; i < 8192; i += 256) {
    const int h = i >> 7, m = i & 127;
    Tt[((size_t)t * 64 + h) * 1024 + mc + m] = bf16rne(lds[m][h]);
  }
}

// ---------------- dense gather GEMM: G[t] = S @ T[t]  (+bias, opt relu) ----------------
// grid 48*63; wave = h-tile. A = S rows (hi+lo), B = Tt[h][m] (k-contiguous).
__global__ void __launch_bounds__(256) k_gmfa(const unsigned short* __restrict__ Shi,
                                              const unsigned short* __restrict__ Slo,
                                              const unsigned short* __restrict__ Tt,
                                              const float* __restrict__ bias,
                                              float* __restrict__ G, int relu) {
  const int t = blockIdx.x / 63, ntile = blockIdx.x % 63;
  const int tid = threadIdx.x, wv = tid >> 6, l = tid & 63;
  const int lr = l & 15, kg = l >> 4;
  const unsigned short* ah = Shi + (size_t)(ntile * 16 + lr) * 1024 + kg * 8;
  const unsigned short* al = Slo + (size_t)(ntile * 16 + lr) * 1024 + kg * 8;
  const unsigned short* bp = Tt + ((size_t)t * 64 + wv * 16 + lr) * 1024 + kg * 8;
  f32x4 acc = {0.f, 0.f, 0.f, 0.f};
#pragma unroll 4
  for (int ks = 0; ks < 32; ++ks) {
    const short8 aH = *(const short8*)(ah + ks * 32);
    const short8 aL = *(const short8*)(al + ks * 32);
    const short8 b  = *(const short8*)(bp + ks * 32);
    acc = __builtin_amdgcn_mfma_f32_16x16x32_bf16(aH, b, acc, 0, 0, 0);
    acc = __builtin_amdgcn_mfma_f32_16x16x32_bf16(aL, b, acc, 0, 0, 0);
  }
  const int h = wv * 16 + lr;
  const float bv = bias[h];
#pragma unroll
  for (int j = 0; j < 4; ++j) {
    const int n = ntile * 16 + kg * 4 + j;
    if (n < N_NODES) {
      float v = acc[j] + bv;
      if (relu) v = fmaxf(v, 0.f);
      G[(size_t)t * 64000 + n * 64 + h] = v;
    }
  }
}

// ---------------- T1 = x @ Wg1 ----------------
__global__ void __launch_bounds__(256) k_t1(const float* __restrict__ x,
                                            const float* __restrict__ Wg1,
                                            float* __restrict__ T1) {
  __shared__ float sWT[H_DIM * 36];     // transposed: sWT[h][k]
  __shared__ float sx[4][DIN];
  const int tid = threadIdx.x, wv = tid >> 6, h = tid & 63;
  for (int i = tid; i < DIN * H_DIM; i += 256) sWT[(i & 63) * 36 + (i >> 6)] = Wg1[i];
  __syncthreads();
  const int r0 = blockIdx.x * 64 + wv * 16;
  const float4* wrow = (const float4*)&sWT[h * 36];
  for (int it = 0; it < 16; ++it) {
    const int r = r0 + it;
    if (h < DIN) sx[wv][h] = x[r * DIN + h];   // wave-local
    float acc = 0.f;
    const float4* xp = (const float4*)&sx[wv][0];
#pragma unroll
    for (int k4 = 0; k4 < 8; ++k4) {
      float4 xv = xp[k4], wv4 = wrow[k4];
      acc += xv.x * wv4.x + xv.y * wv4.y + xv.z * wv4.z + xv.w * wv4.w;
    }
    T1[r * H_DIM + h] = acc;
  }
}

// ---------------- gather fallback (small-ws path only) ----------------
__device__ __forceinline__ float gath_node(const float* __restrict__ Tsrc,
                                           const int* __restrict__ es,
                                           const float* __restrict__ ew,
                                           int cnt, int h) {
  float a0 = 0.f, a1 = 0.f, a2 = 0.f, a3 = 0.f;
  float a4 = 0.f, a5 = 0.f, a6 = 0.f, a7 = 0.f;
  int e = 0;
  if (cnt >= 8) {
    float p0 = Tsrc[es[0] * 64 + h], p1 = Tsrc[es[1] * 64 + h];
    float p2 = Tsrc[es[2] * 64 + h], p3 = Tsrc[es[3] * 64 + h];
    float p4 = Tsrc[es[4] * 64 + h], p5 = Tsrc[es[5] * 64 + h];
    float p6 = Tsrc[es[6] * 64 + h], p7 = Tsrc[es[7] * 64 + h];
    for (e = 8; e + 8 <= cnt; e += 8) {
      float n0 = Tsrc[es[e + 0] * 64 + h], n1 = Tsrc[es[e + 1] * 64 + h];
      float n2 = Tsrc[es[e + 2] * 64 + h], n3 = Tsrc[es[e + 3] * 64 + h];
      float n4 = Tsrc[es[e + 4] * 64 + h], n5 = Tsrc[es[e + 5] * 64 + h];
      float n6 = Tsrc[es[e + 6] * 64 + h], n7 = Tsrc[es[e + 7] * 64 + h];
      a0 += ew[e - 8] * p0; a1 += ew[e - 7] * p1;
      a2 += ew[e - 6] * p2; a3 += ew[e - 5] * p3;
      a4 += ew[e - 4] * p4; a5 += ew[e - 3] * p5;
      a6 += ew[e - 2] * p6; a7 += ew[e - 1] * p7;
      p0 = n0; p1 = n1; p2 = n2; p3 = n3; p4 = n4; p5 = n5; p6 = n6; p7 = n7;
    }
    a0 += ew[e - 8] * p0; a1 += ew[e - 7] * p1;
    a2 += ew[e - 6] * p2; a3 += ew[e - 5] * p3;
    a4 += ew[e - 4] * p4; a5 += ew[e - 3] * p5;
    a6 += ew[e - 2] * p6; a7 += ew[e - 1] * p7;
  }
  for (; e < cnt; ++e) a0 += ew[e] * Tsrc[es[e] * 64 + h];
  return ((a0 + a1) + (a2 + a3)) + ((a4 + a5) + (a6 + a7));
}

#define ECHUNK 768
__global__ void __launch_bounds__(256) k_gath(const float* __restrict__ Tall,
                                              const float* __restrict__ bias,
                                              const int* __restrict__ rowptr,
                                              const int* __restrict__ csrc,
                                              const float* __restrict__ cnorm,
                                              const float* __restrict__ selfn,
                                              float* __restrict__ Dall, int relu) {
  __shared__ int   s_src[ECHUNK];
  __shared__ float s_wt[ECHUNK];
  __shared__ float sb[64];
  const int tid = threadIdx.x, wv = tid >> 6, h = tid & 63;
  if (tid < 64) sb[tid] = bias[tid];
  const int t = blockIdx.x >> 6, nb16 = (blockIdx.x & 63) * 16;
  if (nb16 >= N_NODES) return;
  const float* Tsrc = Tall + t * 64000;
  float* dst = Dall + t * 64000;
  const int nE = (nb16 + 16 < N_NODES) ? nb16 + 16 : N_NODES;
  const int r0 = rowptr[nb16], r1 = rowptr[nE];
  const int tot = r1 - r0;
  const bool fits = (tot <= ECHUNK);
  if (fits)
    for (int i = tid; i < tot; i += 256) { s_src[i] = csrc[r0 + i]; s_wt[i] = cnorm[r0 + i]; }
  __syncthreads();
  for (int i = 0; i < 4; ++i) {
    const int n = nb16 + wv * 4 + i;
    if (n >= N_NODES) continue;
    const int a = rowptr[n], b = rowptr[n + 1];
    float acc = selfn[n] * Tsrc[n * 64 + h];
    if (fits) {
      acc += gath_node(Tsrc, s_src + (a - r0), s_wt + (a - r0), b - a, h);
    } else {
      for (int e = a; e < b; ++e) acc += cnorm[e] * Tsrc[csrc[e] * 64 + h];
    }
    acc += sb[h];
    if (relu) acc = fmaxf(acc, 0.f);
    dst[n * 64 + h] = acc;
  }
}

// ---------------- T2 = G1 @ Wg2 (48000 x 64 x 64) ----------------
__global__ void __launch_bounds__(256) k_mm2(const float* __restrict__ G1,
                                             const float* __restrict__ Wg2,
                                             float* __restrict__ T2) {
  __shared__ float sW[H_DIM * H_DIM];   // [k][h] broadcast form, conflict-free
  __shared__ float sx[4][H_DIM];
  const int tid = threadIdx.x, wv = tid >> 6, h = tid & 63;
  for (int i = tid; i < H_DIM * H_DIM; i += 256) sW[i] = Wg2[i];
  __syncthreads();
  const int r0 = blockIdx.x * 64 + wv * 16;
  for (int it = 0; it < 16; ++it) {
    const int r = r0 + it;
    sx[wv][h] = G1[r * 64 + h];   // wave-local write then read
    float acc = 0.f;
#pragma unroll
    for (int k = 0; k < H_DIM; ++k) acc += sx[wv][k] * sW[k * H_DIM + h];
    T2[r * 64 + h] = acc;
  }
}

// ---------------- LSTM scan (R17 version) ----------------
__global__ void __launch_bounds__(256) k_lstm(const float* __restrict__ G2,
                                              const float* __restrict__ h0,
                                              const float* __restrict__ c0,
                                              const float* __restrict__ Wih,
                                              const float* __restrict__ Whh,
                                              const float* __restrict__ bih,
                                              const float* __restrict__ bhh,
                                              float* __restrict__ hsg,
                                              unsigned short* __restrict__ hsb,
                                              float* __restrict__ outp) {
  const int tid = threadIdx.x, nb = blockIdx.x;
  __shared__ float sh[64];
  __shared__ float sg2[2][64];
  __shared__ float sgates[256];
  float4 Wih4[16], Whh4[16];
  {
    const float4* wp = (const float4*)(Wih + tid * H_DIM);
    const float4* vp = (const float4*)(Whh + tid * H_DIM);
#pragma unroll
    for (int k = 0; k < 16; ++k) { Wih4[k] = wp[k]; Whh4[k] = vp[k]; }
  }
  const float bsum = bih[tid] + bhh[tid];
  float creg = 0.f;
  if (tid < 64) {
    sh[tid] = h0[nb * 64 + tid];
    creg = c0[nb * 64 + tid];
    sg2[0][tid] = G2[nb * 64 + tid];
  }
  __syncthreads();
  for (int t = 0; t < T_STEPS; ++t) {
    const int cur = t & 1;
    float gnext = 0.f;
    if (t < T_STEPS - 1 && tid < 64) gnext = G2[(t + 1) * 64000 + nb * 64 + tid];
    float gv = bsum;
    const float4* gp = (const float4*)&sg2[cur][0];
    const float4* hp = (const float4*)sh;
#pragma unroll
    for (int k = 0; k < 16; ++k) {
      float4 a = gp[k], b = hp[k];
      gv += a.x * Wih4[k].x + a.y * Wih4[k].y + a.z * Wih4[k].z + a.w * Wih4[k].w;
      gv += b.x * Whh4[k].x + b.y * Whh4[k].y + b.z * Whh4[k].z + b.w * Whh4[k].w;
    }
    sgates[tid] = gv;
    __syncthreads();
    if (tid < 64) {
      float iv = sgates[tid], fv = sgates[64 + tid], gg = sgates[128 + tid], ov = sgates[192 + tid];
      float cn = sigmf(fv) * creg + sigmf(iv) * tanhf(gg);
      float hn = sigmf(ov) * tanhf(cn);
      creg = cn;
      sh[tid] = hn;
      if (hsb) {
        hsb[t * 64000 + nb * 64 + tid] = bf16rne(hn);
      } else {
        hsg[t * 64000 + nb * 64 + tid] = hn;
      }
      if (t < T_STEPS - 1) sg2[cur ^ 1][tid] = gnext;
    }
    __syncthreads();
  }
  if (tid < 64) {
    outp[48000 + nb * 64 + tid] = sh[tid];
    outp[48000 + 64000 + nb * 64 + tid] = creg;
  }
}

// ---------------- HS f32 -> bf16 (fallback only) ----------------
__global__ void k_cvt(const float* __restrict__ src, unsigned* __restrict__ dst) {
  const int id = blockIdx.x * 256 + threadIdx.x;
  const float4 v = ((const float4*)src)[id];
  unsigned lo, hi;
  asm("v_cvt_pk_bf16_f32 %0, %1, %2" : "=v"(lo) : "v"(v.x), "v"(v.y));
  asm("v_cvt_pk_bf16_f32 %0, %1, %2" : "=v"(hi) : "v"(v.z), "v"(v.w));
  ((uint2*)dst)[id] = make_uint2(lo, hi);
}

// ---------------- MFMA W-stream gemm (R17 version: part buffer epilogue) ----------------
#define GS_KC 40
__global__ void __launch_bounds__(256) k_gemmS(const unsigned short* __restrict__ hsb,
                                               const float* __restrict__ Wlin,
                                               float* __restrict__ part) {
  __shared__ float4 red[4][3][64];               // 12 KB
  const int tid = threadIdx.x;
  const int kc = blockIdx.x % GS_KC, nt = blockIdx.x / GS_KC;   // nt 0..62
  const int wv = tid >> 6, l = tid & 63;
  const int lr = l & 15, kg = l >> 4;
  const int kcbase = kc * 1600;                  // 64000 / 40

  const unsigned short* ap0 = hsb + (size_t)(0  + lr) * 64000 + kcbase + kg * 8 + wv * 32;
  const unsigned short* ap1 = hsb + (size_t)(16 + lr) * 64000 + kcbase + kg * 8 + wv * 32;
  const unsigned short* ap2 = hsb + (size_t)(32 + lr) * 64000 + kcbase + kg * 8 + wv * 32;
  int nrow = nt * 16 + lr; if (nrow > N_NODES - 1) nrow = N_NODES - 1;
  const float* bp = Wlin + (size_t)nrow * 64000 + kcbase + kg * 8 + wv * 32;

  f32x4 acc0 = {0.f, 0.f, 0.f, 0.f}, acc1 = acc0, acc2 = acc0;

  for (int s = wv; s < 50; s += 4) {
    const short8 a0 = *(const short8*)ap0;
    const short8 a1 = *(const short8*)ap1;
    const short8 a2 = *(const short8*)ap2;
    const float4 b0 = *(const float4*)bp;
    const float4 b1 = *(const float4*)(bp + 4);
    unsigned p0, p1, p2, p3;
    asm("v_cvt_pk_bf16_f32 %0, %1, %2" : "=v"(p0) : "v"(b0.x), "v"(b0.y));
    asm("v_cvt_pk_bf16_f32 %0, %1, %2" : "=v"(p1) : "v"(b0.z), "v"(b0.w));
    asm("v_cvt_pk_bf16_f32 %0, %1, %2" : "=v"(p2) : "v"(b1.x), "v"(b1.y));
    asm("v_cvt_pk_bf16_f32 %0, %1, %2" : "=v"(p3) : "v"(b1.z), "v"(b1.w));
    uint32x4 bu = {p0, p1, p2, p3};
    const short8 bs = __builtin_bit_cast(short8, bu);
    acc0 = __builtin_amdgcn_mfma_f32_16x16x32_bf16(a0, bs, acc0, 0, 0, 0);
    acc1 = __builtin_amdgcn_mfma_f32_16x16x32_bf16(a1, bs, acc1, 0, 0, 0);
    acc2 = __builtin_amdgcn_mfma_f32_16x16x32_bf16(a2, bs, acc2, 0, 0, 0);
    ap0 += 128; ap1 += 128; ap2 += 128; bp += 128;
  }

  red[wv][0][l] = make_float4(acc0[0], acc0[1], acc0[2], acc0[3]);
  red[wv][1][l] = make_float4(acc1[0], acc1[1], acc1[2], acc1[3]);
  red[wv][2][l] = make_float4(acc2[0], acc2[1], acc2[2], acc2[3]);
  __syncthreads();
  if (wv < 3) {
    const float4 r0 = red[0][wv][l], r1 = red[1][wv][l];
    const float4 r2 = red[2][wv][l], r3 = red[3][wv][l];
    const float4 s4 = make_float4(r0.x + r1.x + r2.x + r3.x,
                                  r0.y + r1.y + r2.y + r3.y,
                                  r0.z + r1.z + r2.z + r3.z,
                                  r0.w + r1.w + r2.w + r3.w);
    const int n = nt * 16 + lr;
    if (n < N_NODES) {
      const int trow = wv * 16 + kg * 4;
      float* base = part + (size_t)(kc * 48 + trow) * 1000 + n;
      base[0]    = s4.x;
      base[1000] = s4.y;
      base[2000] = s4.z;
      base[3000] = s4.w;
    }
  }
}

// ---------------- fallback gemm (kc=16, small-ws path) ----------------
__global__ void __launch_bounds__(256) k_gemmM(const unsigned short* __restrict__ hsb,
                                               const float* __restrict__ Wlin,
                                               float* __restrict__ part) {
  const int tid = threadIdx.x;
  const int kc = blockIdx.x & 15, nt = blockIdx.x >> 4;
  const int wv = tid >> 6, l = tid & 63;
  const int lr = l & 15, kg = l >> 4;
  const int kcbase = kc * 4000;
  const int kp = kc * 4 + wv;

  const unsigned short* ap0 = hsb + (size_t)(0  + lr) * 64000 + kcbase + kg * 8 + wv * 32;
  const unsigned short* ap1 = hsb + (size_t)(16 + lr) * 64000 + kcbase + kg * 8 + wv * 32;
  const unsigned short* ap2 = hsb + (size_t)(32 + lr) * 64000 + kcbase + kg * 8 + wv * 32;
  int nrow = nt * 16 + lr; if (nrow > N_NODES - 1) nrow = N_NODES - 1;
  const float* bp = Wlin + (size_t)nrow * 64000 + kcbase + kg * 8 + wv * 32;

  f32x4 acc0 = {0.f, 0.f, 0.f, 0.f}, acc1 = acc0, acc2 = acc0;

  for (int s = wv; s < 125; s += 4) {
    const short8 a0 = *(const short8*)ap0;
    const short8 a1 = *(const short8*)ap1;
    const short8 a2 = *(const short8*)ap2;
    const float4 b0 = *(const float4*)bp;
    const float4 b1 = *(const float4*)(bp + 4);
    unsigned p0, p1, p2, p3;
    asm("v_cvt_pk_bf16_f32 %0, %1, %2" : "=v"(p0) : "v"(b0.x), "v"(b0.y));
    asm("v_cvt_pk_bf16_f32 %0, %1, %2" : "=v"(p1) : "v"(b0.z), "v"(b0.w));
    asm("v_cvt_pk_bf16_f32 %0, %1, %2" : "=v"(p2) : "v"(b1.x), "v"(b1.y));
    asm("v_cvt_pk_bf16_f32 %0, %1, %2" : "=v"(p3) : "v"(b1.z), "v"(b1.w));
    uint32x4 bu = {p0, p1, p2, p3};
    const short8 bs = __builtin_bit_cast(short8, bu);
    acc0 = __builtin_amdgcn_mfma_f32_16x16x32_bf16(a0, bs, acc0, 0, 0, 0);
    acc1 = __builtin_amdgcn_mfma_f32_16x16x32_bf16(a1, bs, acc1, 0, 0, 0);
    acc2 = __builtin_amdgcn_mfma_f32_16x16x32_bf16(a2, bs, acc2, 0, 0, 0);
    ap0 += 128; ap1 += 128; ap2 += 128; bp += 128;
  }

  const int n = nt * 16 + lr;
  if (n < N_NODES) {
    const int trow = kg * 4;
    float* base = part + (size_t)(kp * 48) * 1000 + n;
#pragma unroll
    for (int j = 0; j < 4; ++j) base[(0  + trow + j) * 1000] = acc0[j];
#pragma unroll
    for (int j = 0; j < 4; ++j) base[(16 + trow + j) * 1000] = acc1[j];
#pragma unroll
    for (int j = 0; j < 4; ++j) base[(32 + trow + j) * 1000] = acc2[j];
  }
}

__global__ void k_reduce(const float* __restrict__ part, const float* __restrict__ blin,
                         float* __restrict__ outp, int np) {
  const int id = blockIdx.x * 256 + threadIdx.x;
  if (id >= T_STEPS * N_NODES) return;
  const int t = id / N_NODES, n = id - t * N_NODES;
  float s = blin[n];
  for (int kp = 0; kp < np; ++kp) s += part[(size_t)(kp * 48 + t) * 1000 + n];
  outp[id] = s;
}

// ---------------- launch ----------------
extern "C" void kernel_launch(void* const* d_in, const int* in_sizes, int n_in,
                              void* d_out, int out_size, void* d_ws, size_t ws_size,
                              hipStream_t stream) {
  const float* x    = (const float*)d_in[0];
  const int*   ei   = (const int*)d_in[1];
  const float* h0   = (const float*)d_in[2];
  const float* c0   = (const float*)d_in[3];
  const float* Wg1  = (const float*)d_in[4];
  const float* bg1  = (const float*)d_in[5];
  const float* Wg2  = (const float*)d_in[6];
  const float* bg2  = (const float*)d_in[7];
  const float* Wih  = (const float*)d_in[8];
  const float* Whh  = (const float*)d_in[9];
  const float* bih  = (const float*)d_in[10];
  const float* bhh  = (const float*)d_in[11];
  const float* Wlin = (const float*)d_in[12];
  const float* blin = (const float*)d_in[13];
  float* outp = (float*)d_out;
  float* wsf  = (float*)d_ws;
  int*   wsi  = (int*)d_ws;

  int*   indeg  = wsi + O_INDEG;
  int*   fill   = wsi + O_FILL;
  int*   rowptr = wsi + O_ROWPTR;
  int*   csrc   = wsi + O_CSRC;
  float* cnorm  = wsf + O_CNORM;
  float* dinv   = wsf + O_DINV;
  float* selfn  = wsf + O_SELF;
  float* buf0   = wsf + O_BUF0;
  float* buf1   = wsf + O_BUF1;

  const bool big = ws_size >= WS_NEED_BIG;

  k_zero<<<8, 256, 0, stream>>>(wsi);
  k_count<<<(E_EDGES + 255) / 256, 256, 0, stream>>>(ei, indeg);
  k_scan<<<1, 1024, 0, stream>>>(indeg, rowptr, dinv, selfn);
  k_scatter<<<(E_EDGES + 255) / 256, 256, 0, stream>>>(ei, rowptr, fill, dinv, csrc, cnorm);

  if (big) {
    unsigned short* Shi = (unsigned short*)(wsf + O_SHI);
    unsigned short* Slo = (unsigned short*)(wsf + O_SLO);
    unsigned short* Tt  = (unsigned short*)(wsf + O_TT);
    unsigned short* hsb = (unsigned short*)(wsf + O_HSB);

    k_sden<<<1008, 256, 0, stream>>>(rowptr, csrc, cnorm, selfn, Shi, Slo);
    k_t1<<<750, 256, 0, stream>>>(x, Wg1, buf0);                          // T1 f32
    k_tr<<<384, 256, 0, stream>>>(buf0, Tt);                              // T1 -> Tt
    k_gmfa<<<48 * 63, 256, 0, stream>>>(Shi, Slo, Tt, bg1, buf1, 1);      // G1
    k_mm2<<<750, 256, 0, stream>>>(buf1, Wg2, buf0);                      // T2 f32
    k_tr<<<384, 256, 0, stream>>>(buf0, Tt);                              // T2 -> Tt
    k_gmfa<<<48 * 63, 256, 0, stream>>>(Shi, Slo, Tt, bg2, buf1, 0);      // G2
    k_lstm<<<1000, 256, 0, stream>>>(buf1, h0, c0, Wih, Whh, bih, bhh,
                                     buf0, hsb, outp);                    // HS bf16
    k_gemmS<<<GS_KC * 63, 256, 0, stream>>>(hsb, Wlin, buf0);
    k_reduce<<<(T_STEPS * N_NODES + 255) / 256, 256, 0, stream>>>(buf0, blin, outp, GS_KC);
  } else {
    k_t1<<<750, 256, 0, stream>>>(x, Wg1, buf0);
    k_gath<<<3072, 256, 0, stream>>>(buf0, bg1, rowptr, csrc, cnorm, selfn, buf1, 1);
    k_mm2<<<750, 256, 0, stream>>>(buf1, Wg2, buf0);
    k_gath<<<3072, 256, 0, stream>>>(buf0, bg2, rowptr, csrc, cnorm, selfn, buf1, 0);
    k_lstm<<<1000, 256, 0, stream>>>(buf1, h0, c0, Wih, Whh, bih, bhh,
                                     buf0, (unsigned short*)nullptr, outp);
    k_cvt<<<3000, 256, 0, stream>>>(buf0, (unsigned*)buf1);
    k_gemmM<<<16 * 63, 256, 0, stream>>>((const unsigned short*)buf1, Wlin, buf0);
    k_reduce<<<(T_STEPS * N_NODES + 255) / 256, 256, 0, stream>>>(buf0, blin, outp, 64);
  }
}

// Round 20
// 356.067 us; speedup vs baseline: 1.5767x; 1.5767x over previous
//
#include <hip/hip_runtime.h>
#include <math.h>

#define T_STEPS 48
#define N_NODES 1000
#define E_EDGES 32000
#define DIN     32
#define H_DIM   64

// ---- workspace layout (4-byte units) ----
#define O_INDEG  0         // int[1000]
#define O_FILL   1024      // int[1000]
#define O_ROWPTR 2048      // int[1001]
#define O_CSRC   4096      // int[32000]
#define O_CNORM  36864     // f32[32000]
#define O_DINV   69632     // f32[1000]
#define O_SELF   70656     // f32[1000]
#define O_BUF0   71680                    // f32[48*64000]  T1 -> T2 -> part
#define O_BUF1   (71680 + 3072000)        // f32[48*64000]  G1 -> G2
#define O_HSB    (71680 + 6144000)        // bf16[48*64000] HS (big path)
#define WS_NEED_HSB ((size_t)(O_HSB + 1536000) * 4)

typedef __attribute__((ext_vector_type(8))) short short8;       // 8 bf16
typedef __attribute__((ext_vector_type(4))) float f32x4;
typedef __attribute__((ext_vector_type(4))) unsigned int uint32x4;

__device__ __forceinline__ float sigmf(float v) { return 1.0f / (1.0f + __expf(-v)); }

// ---------------- setup ----------------
__global__ void k_zero(int* __restrict__ p) { p[blockIdx.x * 256 + threadIdx.x] = 0; }

__global__ void k_count(const int* __restrict__ ei, int* __restrict__ indeg) {
  int e = blockIdx.x * 256 + threadIdx.x;
  if (e < E_EDGES) atomicAdd(&indeg[ei[E_EDGES + e]], 1);
}

__global__ void k_scan(const int* __restrict__ indeg, int* __restrict__ rowptr,
                       float* __restrict__ dinv, float* __restrict__ selfn) {
  __shared__ int sdat[1024];
  int tid = threadIdx.x;
  int v = (tid < N_NODES) ? indeg[tid] : 0;
  sdat[tid] = v;
  __syncthreads();
  for (int off = 1; off < 1024; off <<= 1) {
    int add = (tid >= off) ? sdat[tid - off] : 0;
    __syncthreads();
    sdat[tid] += add;
    __syncthreads();
  }
  if (tid < N_NODES) {
    rowptr[tid + 1] = sdat[tid];
    float di = rsqrtf((float)(v + 1));
    dinv[tid] = di;
    selfn[tid] = di * di;
  }
  if (tid == 0) rowptr[0] = 0;
}

__global__ void k_scatter(const int* __restrict__ ei, const int* __restrict__ rowptr,
                          int* __restrict__ fill, const float* __restrict__ dinv,
                          int* __restrict__ csrc, float* __restrict__ cnorm) {
  int e = blockIdx.x * 256 + threadIdx.x;
  if (e >= E_EDGES) return;
  int s = ei[e], d = ei[E_EDGES + e];
  int pos = atomicAdd(&fill[d], 1);
  int idx = rowptr[d] + pos;
  csrc[idx] = s;
  cnorm[idx] = dinv[s] * dinv[d];
}

// ---------------- T1 = x @ Wg1 ----------------
__global__ void __launch_bounds__(256) k_t1(const float* __restrict__ x,
                                            const float* __restrict__ Wg1,
                                            float* __restrict__ T1) {
  __shared__ float sWT[H_DIM * 36];     // transposed: sWT[h][k]
  __shared__ float sx[4][DIN];
  const int tid = threadIdx.x, wv = tid >> 6, h = tid & 63;
  for (int i = tid; i < DIN * H_DIM; i += 256) sWT[(i & 63) * 36 + (i >> 6)] = Wg1[i];
  __syncthreads();
  const int r0 = blockIdx.x * 64 + wv * 16;
  const float4* wrow = (const float4*)&sWT[h * 36];
  for (int it = 0; it < 16; ++it) {
    const int r = r0 + it;
    if (h < DIN) sx[wv][h] = x[r * DIN + h];   // wave-local
    float acc = 0.f;
    const float4* xp = (const float4*)&sx[wv][0];
#pragma unroll
    for (int k4 = 0; k4 < 8; ++k4) {
      float4 xv = xp[k4], wv4 = wrow[k4];
      acc += xv.x * wv4.x + xv.y * wv4.y + xv.z * wv4.z + xv.w * wv4.w;
    }
    T1[r * H_DIM + h] = acc;
  }
}

// ---------------- gather (8-deep rotating prefetch) ----------------
__device__ __forceinline__ float gath_node(const float* __restrict__ Tsrc,
                                           const int* __restrict__ es,
                                           const float* __restrict__ ew,
                                           int cnt, int h) {
  float a0 = 0.f, a1 = 0.f, a2 = 0.f, a3 = 0.f;
  float a4 = 0.f, a5 = 0.f, a6 = 0.f, a7 = 0.f;
  int e = 0;
  if (cnt >= 8) {
    float p0 = Tsrc[es[0] * 64 + h], p1 = Tsrc[es[1] * 64 + h];
    float p2 = Tsrc[es[2] * 64 + h], p3 = Tsrc[es[3] * 64 + h];
    float p4 = Tsrc[es[4] * 64 + h], p5 = Tsrc[es[5] * 64 + h];
    float p6 = Tsrc[es[6] * 64 + h], p7 = Tsrc[es[7] * 64 + h];
    for (e = 8; e + 8 <= cnt; e += 8) {
      float n0 = Tsrc[es[e + 0] * 64 + h], n1 = Tsrc[es[e + 1] * 64 + h];
      float n2 = Tsrc[es[e + 2] * 64 + h], n3 = Tsrc[es[e + 3] * 64 + h];
      float n4 = Tsrc[es[e + 4] * 64 + h], n5 = Tsrc[es[e + 5] * 64 + h];
      float n6 = Tsrc[es[e + 6] * 64 + h], n7 = Tsrc[es[e + 7] * 64 + h];
      a0 += ew[e - 8] * p0; a1 += ew[e - 7] * p1;
      a2 += ew[e - 6] * p2; a3 += ew[e - 5] * p3;
      a4 += ew[e - 4] * p4; a5 += ew[e - 3] * p5;
      a6 += ew[e - 2] * p6; a7 += ew[e - 1] * p7;
      p0 = n0; p1 = n1; p2 = n2; p3 = n3; p4 = n4; p5 = n5; p6 = n6; p7 = n7;
    }
    a0 += ew[e - 8] * p0; a1 += ew[e - 7] * p1;
    a2 += ew[e - 6] * p2; a3 += ew[e - 5] * p3;
    a4 += ew[e - 4] * p4; a5 += ew[e - 3] * p5;
    a6 += ew[e - 2] * p6; a7 += ew[e - 1] * p7;
  }
  for (; e < cnt; ++e) a0 += ew[e] * Tsrc[es[e] * 64 + h];
  return ((a0 + a1) + (a2 + a3)) + ((a4 + a5) + (a6 + a7));
}

#define ECHUNK 768
__global__ void __launch_bounds__(256) k_gath(const float* __restrict__ Tall,
                                              const float* __restrict__ bias,
                                              const int* __restrict__ rowptr,
                                              const int* __restrict__ csrc,
                                              const float* __restrict__ cnorm,
                                              const float* __restrict__ selfn,
                                              float* __restrict__ Dall, int relu) {
  __shared__ int   s_src[ECHUNK];
  __shared__ float s_wt[ECHUNK];
  __shared__ float sb[64];
  const int tid = threadIdx.x, wv = tid >> 6, h = tid & 63;
  if (tid < 64) sb[tid] = bias[tid];
  const int t = blockIdx.x >> 6, nb16 = (blockIdx.x & 63) * 16;
  if (nb16 >= N_NODES) return;
  const float* Tsrc = Tall + t * 64000;
  float* dst = Dall + t * 64000;
  const int nE = (nb16 + 16 < N_NODES) ? nb16 + 16 : N_NODES;
  const int r0 = rowptr[nb16], r1 = rowptr[nE];
  const int tot = r1 - r0;
  const bool fits = (tot <= ECHUNK);
  if (fits)
    for (int i = tid; i < tot; i += 256) { s_src[i] = csrc[r0 + i]; s_wt[i] = cnorm[r0 + i]; }
  __syncthreads();
  for (int i = 0; i < 4; ++i) {
    const int n = nb16 + wv * 4 + i;
    if (n >= N_NODES) continue;
    const int a = rowptr[n], b = rowptr[n + 1];
    float acc = selfn[n] * Tsrc[n * 64 + h];
    if (fits) {
      acc += gath_node(Tsrc, s_src + (a - r0), s_wt + (a - r0), b - a, h);
    } else {
      for (int e = a; e < b; ++e) acc += cnorm[e] * Tsrc[csrc[e] * 64 + h];
    }
    acc += sb[h];
    if (relu) acc = fmaxf(acc, 0.f);
    dst[n * 64 + h] = acc;
  }
}

// ---------------- T2 = G1 @ Wg2 (48000 x 64 x 64) ----------------
__global__ void __launch_bounds__(256) k_mm2(const float* __restrict__ G1,
                                             const float* __restrict__ Wg2,
                                             float* __restrict__ T2) {
  __shared__ float sW[H_DIM * H_DIM];   // [k][h] broadcast form, conflict-free
  __shared__ float sx[4][H_DIM];
  const int tid = threadIdx.x, wv = tid >> 6, h = tid & 63;
  for (int i = tid; i < H_DIM * H_DIM; i += 256) sW[i] = Wg2[i];
  __syncthreads();
  const int r0 = blockIdx.x * 64 + wv * 16;
  for (int it = 0; it < 16; ++it) {
    const int r = r0 + it;
    sx[wv][h] = G1[r * 64 + h];   // wave-local write then read
    float acc = 0.f;
#pragma unroll
    for (int k = 0; k < H_DIM; ++k) acc += sx[wv][k] * sW[k * H_DIM + h];
    T2[r * 64 + h] = acc;
  }
}

// ---------------- LSTM scan: 1 node / block; writes bf16 HS directly ----------------
__global__ void __launch_bounds__(256) k_lstm(const float* __restrict__ G2,
                                              const float* __restrict__ h0,
                                              const float* __restrict__ c0,
                                              const float* __restrict__ Wih,
                                              const float* __restrict__ Whh,
                                              const float* __restrict__ bih,
                                              const float* __restrict__ bhh,
                                              float* __restrict__ hsg,
                                              unsigned short* __restrict__ hsb,
                                              float* __restrict__ outp) {
  const int tid = threadIdx.x, nb = blockIdx.x;
  __shared__ float sh[64];
  __shared__ float sg2[2][64];
  __shared__ float sgates[256];
  float4 Wih4[16], Whh4[16];
  {
    const float4* wp = (const float4*)(Wih + tid * H_DIM);
    const float4* vp = (const float4*)(Whh + tid * H_DIM);
#pragma unroll
    for (int k = 0; k < 16; ++k) { Wih4[k] = wp[k]; Whh4[k] = vp[k]; }
  }
  const float bsum = bih[tid] + bhh[tid];
  float creg = 0.f;
  if (tid < 64) {
    sh[tid] = h0[nb * 64 + tid];
    creg = c0[nb * 64 + tid];
    sg2[0][tid] = G2[nb * 64 + tid];
  }
  __syncthreads();
  for (int t = 0; t < T_STEPS; ++t) {
    const int cur = t & 1;
    float gnext = 0.f;
    if (t < T_STEPS - 1 && tid < 64) gnext = G2[(t + 1) * 64000 + nb * 64 + tid];
    float gv = bsum;
    const float4* gp = (const float4*)&sg2[cur][0];
    const float4* hp = (const float4*)sh;
#pragma unroll
    for (int k = 0; k < 16; ++k) {
      float4 a = gp[k], b = hp[k];
      gv += a.x * Wih4[k].x + a.y * Wih4[k].y + a.z * Wih4[k].z + a.w * Wih4[k].w;
      gv += b.x * Whh4[k].x + b.y * Whh4[k].y + b.z * Whh4[k].z + b.w * Whh4[k].w;
    }
    sgates[tid] = gv;
    __syncthreads();
    if (tid < 64) {
      float iv = sgates[tid], fv = sgates[64 + tid], gg = sgates[128 + tid], ov = sgates[192 + tid];
      float cn = sigmf(fv) * creg + sigmf(iv) * tanhf(gg);
      float hn = sigmf(ov) * tanhf(cn);
      creg = cn;
      sh[tid] = hn;
      if (hsb) {
        unsigned u = __float_as_uint(hn);
        u += 0x7fff + ((u >> 16) & 1);                 // RNE
        hsb[t * 64000 + nb * 64 + tid] = (unsigned short)(u >> 16);
      } else {
        hsg[t * 64000 + nb * 64 + tid] = hn;
      }
      if (t < T_STEPS - 1) sg2[cur ^ 1][tid] = gnext;
    }
    __syncthreads();
  }
  if (tid < 64) {
    outp[48000 + nb * 64 + tid] = sh[tid];
    outp[48000 + 64000 + nb * 64 + tid] = creg;
  }
}

// ---------------- HS f32 -> bf16 (fallback only) ----------------
__global__ void k_cvt(const float* __restrict__ src, unsigned* __restrict__ dst) {
  const int id = blockIdx.x * 256 + threadIdx.x;
  const float4 v = ((const float4*)src)[id];
  unsigned lo, hi;
  asm("v_cvt_pk_bf16_f32 %0, %1, %2" : "=v"(lo) : "v"(v.x), "v"(v.y));
  asm("v_cvt_pk_bf16_f32 %0, %1, %2" : "=v"(hi) : "v"(v.z), "v"(v.w));
  ((uint2*)dst)[id] = make_uint2(lo, hi);
}

// ---------------- final projection: out = HS @ Wlin^T via bf16 MFMA ----------------
// Pure W-stream, no LDS/barriers. R20: unroll 2 on the K-loop so the compiler
// can co-issue two iterations' loads (cheap 2-deep pipeline without named regs).
__global__ void __launch_bounds__(256) k_gemmM(const unsigned short* __restrict__ hsb,
                                               const float* __restrict__ Wlin,
                                               float* __restrict__ part) {
  const int tid = threadIdx.x;
  const int kc = blockIdx.x & 15, nt = blockIdx.x >> 4;   // kc->XCD; nt 0..62
  const int wv = tid >> 6, l = tid & 63;
  const int lr = l & 15, kg = l >> 4;
  const int kcbase = kc * 4000;
  const int kp = kc * 4 + wv;

  const unsigned short* ap0 = hsb + (size_t)(0  + lr) * 64000 + kcbase + kg * 8 + wv * 32;
  const unsigned short* ap1 = hsb + (size_t)(16 + lr) * 64000 + kcbase + kg * 8 + wv * 32;
  const unsigned short* ap2 = hsb + (size_t)(32 + lr) * 64000 + kcbase + kg * 8 + wv * 32;
  int nrow = nt * 16 + lr; if (nrow > N_NODES - 1) nrow = N_NODES - 1;
  const float* bp = Wlin + (size_t)nrow * 64000 + kcbase + kg * 8 + wv * 32;

  f32x4 acc0 = {0.f, 0.f, 0.f, 0.f}, acc1 = acc0, acc2 = acc0;

#pragma unroll 2
  for (int s = wv; s < 125; s += 4) {
    const short8 a0 = *(const short8*)ap0;
    const short8 a1 = *(const short8*)ap1;
    const short8 a2 = *(const short8*)ap2;
    const float4 b0 = *(const float4*)bp;
    const float4 b1 = *(const float4*)(bp + 4);
    unsigned p0, p1, p2, p3;
    asm("v_cvt_pk_bf16_f32 %0, %1, %2" : "=v"(p0) : "v"(b0.x), "v"(b0.y));
    asm("v_cvt_pk_bf16_f32 %0, %1, %2" : "=v"(p1) : "v"(b0.z), "v"(b0.w));
    asm("v_cvt_pk_bf16_f32 %0, %1, %2" : "=v"(p2) : "v"(b1.x), "v"(b1.y));
    asm("v_cvt_pk_bf16_f32 %0, %1, %2" : "=v"(p3) : "v"(b1.z), "v"(b1.w));
    uint32x4 bu = {p0, p1, p2, p3};
    const short8 bs = __builtin_bit_cast(short8, bu);
    acc0 = __builtin_amdgcn_mfma_f32_16x16x32_bf16(a0, bs, acc0, 0, 0, 0);
    acc1 = __builtin_amdgcn_mfma_f32_16x16x32_bf16(a1, bs, acc1, 0, 0, 0);
    acc2 = __builtin_amdgcn_mfma_f32_16x16x32_bf16(a2, bs, acc2, 0, 0, 0);
    ap0 += 128; ap1 += 128; ap2 += 128; bp += 128;
  }

  const int n = nt * 16 + lr;
  if (n < N_NODES) {
    const int trow = kg * 4;
    float* base = part + (size_t)(kp * 48) * 1000 + n;
#pragma unroll
    for (int j = 0; j < 4; ++j) base[(0  + trow + j) * 1000] = acc0[j];
#pragma unroll
    for (int j = 0; j < 4; ++j) base[(16 + trow + j) * 1000] = acc1[j];
#pragma unroll
    for (int j = 0; j < 4; ++j) base[(32 + trow + j) * 1000] = acc2[j];
  }
}

__global__ void k_reduce(const float* __restrict__ part, const float* __restrict__ blin,
                         float* __restrict__ outp) {
  const int id = blockIdx.x * 256 + threadIdx.x;
  if (id >= T_STEPS * N_NODES) return;
  const int t = id / N_NODES, n = id - t * N_NODES;
  float s = blin[n];
#pragma unroll 8
  for (int kp = 0; kp < 64; ++kp) s += part[(size_t)(kp * 48 + t) * 1000 + n];
  outp[id] = s;
}

// ---------------- launch ----------------
extern "C" void kernel_launch(void* const* d_in, const int* in_sizes, int n_in,
                              void* d_out, int out_size, void* d_ws, size_t ws_size,
                              hipStream_t stream) {
  const float* x    = (const float*)d_in[0];
  const int*   ei   = (const int*)d_in[1];
  const float* h0   = (const float*)d_in[2];
  const float* c0   = (const float*)d_in[3];
  const float* Wg1  = (const float*)d_in[4];
  const float* bg1  = (const float*)d_in[5];
  const float* Wg2  = (const float*)d_in[6];
  const float* bg2  = (const float*)d_in[7];
  const float* Wih  = (const float*)d_in[8];
  const float* Whh  = (const float*)d_in[9];
  const float* bih  = (const float*)d_in[10];
  const float* bhh  = (const float*)d_in[11];
  const float* Wlin = (const float*)d_in[12];
  const float* blin = (const float*)d_in[13];
  float* outp = (float*)d_out;
  float* wsf  = (float*)d_ws;
  int*   wsi  = (int*)d_ws;

  int*   indeg  = wsi + O_INDEG;
  int*   fill   = wsi + O_FILL;
  int*   rowptr = wsi + O_ROWPTR;
  int*   csrc   = wsi + O_CSRC;
  float* cnorm  = wsf + O_CNORM;
  float* dinv   = wsf + O_DINV;
  float* selfn  = wsf + O_SELF;
  float* buf0   = wsf + O_BUF0;
  float* buf1   = wsf + O_BUF1;

  const bool big = ws_size >= WS_NEED_HSB;

  k_zero<<<8, 256, 0, stream>>>(wsi);
  k_count<<<(E_EDGES + 255) / 256, 256, 0, stream>>>(ei, indeg);
  k_scan<<<1, 1024, 0, stream>>>(indeg, rowptr, dinv, selfn);
  k_scatter<<<(E_EDGES + 255) / 256, 256, 0, stream>>>(ei, rowptr, fill, dinv, csrc, cnorm);

  k_t1<<<750, 256, 0, stream>>>(x, Wg1, buf0);
  k_gath<<<3072, 256, 0, stream>>>(buf0, bg1, rowptr, csrc, cnorm, selfn, buf1, 1);  // G1
  k_mm2<<<750, 256, 0, stream>>>(buf1, Wg2, buf0);                                   // T2
  k_gath<<<3072, 256, 0, stream>>>(buf0, bg2, rowptr, csrc, cnorm, selfn, buf1, 0);  // G2

  unsigned short* hsb;
  if (big) {
    hsb = (unsigned short*)(wsf + O_HSB);
    k_lstm<<<1000, 256, 0, stream>>>(buf1, h0, c0, Wih, Whh, bih, bhh,
                                     buf0, hsb, outp);           // bf16 HS direct
  } else {
    k_lstm<<<1000, 256, 0, stream>>>(buf1, h0, c0, Wih, Whh, bih, bhh,
                                     buf0, (unsigned short*)nullptr, outp);  // f32 HS
    k_cvt<<<3000, 256, 0, stream>>>(buf0, (unsigned*)buf1);
    hsb = (unsigned short*)buf1;
  }
  k_gemmM<<<16 * 63, 256, 0, stream>>>(hsb, Wlin, buf0);
  k_reduce<<<(T_STEPS * N_NODES + 255) / 256, 256, 0, stream>>>(buf0, blin, outp);
}